// Round 10
// baseline (408.273 us; speedup 1.0000x reference)
//
#include <hip/hip_runtime.h>
#include <hip/hip_fp16.h>

// ---------------------------------------------------------------------------
// ContrastiveGNN: 2-layer GCN + global mean pool + linear head.
//
//   hs1[v]   = (x[v] @ W1) * dinv[v]            (MFMA f16 GEMM, f32 acc, f16 out)
//   g1[v]    = relu(dinv[v]*(hs1[v] + sum_{u->v} hs1[u]) + b1)
//   gs1[v]   = g1[v] * dinv[v]                  (gather1, f32 math, f16 store)
//   a2[v]    = dinv[v]*(gs1[v] + sum_{u->v} gs1[u])
//   pool[g]  = mean_{v in g} a2[v]              (gather2, LDS-pooled atomics)
//   emb      = pool @ W2 + b2 ; logits = emb @ Wg + bg   (tiny head)
//
// Build pipeline (r10): k1 bucket-sorts edges into block-private regions
// (PACKED 4B: src|((dst&255)<<17)) and counts per-node degree via global
// atomics; k3b scans degrees per bucket (computing its own bucket base);
// k3c scatters adj into bucket-private regions.  histT/sstartT chunk-major
// so k1 writes coalesced.  ONE memset covers all zeroed buffers.
// 8 dispatches total (was 14).
//
// Gathers (VERIFIED r4/r5/r7): 1 wave/node, lane holds features
// [2*lane, 2*lane+1] (half2), software-pipelined 8-deep.  Gather L2-fill
// sits at ~2-2.5 TB/s across all configs (r5-r9) -> treated as the random-
// 256B-row ceiling; structure frozen.
// DO NOT reintroduce the half-wave + __shfl restructure (rounds 2/3).
// DO NOT trade wave count for per-wave MLP (r6: conserved concurrency).
// ---------------------------------------------------------------------------

#define TPB 256
#define CHUNK 4096          // edges per K1 block
#define MAXB 512            // max buckets AND max chunks
#define SUBS 8              // sub-blocks per bucket in K3c
#define SRCMASK 0x1FFFF     // 17 bits: n < 131072

typedef _Float16 half8 __attribute__((ext_vector_type(8)));
typedef float floatx4 __attribute__((ext_vector_type(4)));

// exclusive scan of a[0..512) in LDS, 256 threads; part[255] = total.
__device__ __forceinline__ void exscan512(int* a, int* part, int t) {
    int x0 = a[2 * t], x1 = a[2 * t + 1];
    part[t] = x0 + x1;
    __syncthreads();
    for (int off = 1; off < 256; off <<= 1) {
        int v = (t >= off) ? part[t - off] : 0;
        __syncthreads();
        part[t] += v;
        __syncthreads();
    }
    int base = (t > 0) ? part[t - 1] : 0;
    a[2 * t] = base;
    a[2 * t + 1] = base + x0;
    __syncthreads();
}

// ---- K1: per-chunk bucket sort (bucket = dst>>8) + per-node degree ----
__global__ __launch_bounds__(256) void k1_bucket(const int* __restrict__ ei, int E,
                                                 int B, int nchunks,
                                                 unsigned* __restrict__ sorted,
                                                 int* __restrict__ histT,
                                                 int* __restrict__ sstartT,
                                                 int* __restrict__ bucketTot,
                                                 int* __restrict__ deg) {
    __shared__ int hcnt[MAXB], hoff[MAXB], hcur[MAXB], part[256];
    int c = blockIdx.x, t = threadIdx.x;
    int e0 = c * CHUNK;
    int m = E - e0; if (m > CHUNK) m = CHUNK;
    for (int i = t; i < MAXB; i += 256) { hcnt[i] = 0; hcur[i] = 0; }
    __syncthreads();
    for (int i = t; i < m; i += 256) {
        int dst = ei[E + e0 + i];
        atomicAdd(&hcnt[dst >> 8], 1);
        atomicAdd(&deg[dst], 1);                 // global, fire-and-forget
    }
    __syncthreads();
    for (int i = t; i < MAXB; i += 256) hoff[i] = hcnt[i];
    __syncthreads();
    exscan512(hoff, part, t);
    for (int i = t; i < B; i += 256) {           // chunk-major: coalesced rows
        histT[(size_t)c * B + i]   = hcnt[i];
        sstartT[(size_t)c * B + i] = e0 + hoff[i];
        if (hcnt[i] > 0) atomicAdd(&bucketTot[i], hcnt[i]);
    }
    __syncthreads();
    for (int i = t; i < m; i += 256) {
        int src = ei[e0 + i], dst = ei[E + e0 + i];
        int b = dst >> 8;
        int pos = e0 + hoff[b] + atomicAdd(&hcur[b], 1);
        sorted[pos] = (unsigned)src | ((unsigned)(dst & 255) << 17);
    }
}

// ---- K3b: per-bucket scan -> offs/dinv/cnt (computes own bucket base) ----
__global__ __launch_bounds__(256) void k3b_offs(const int* __restrict__ deg,
                                                const int* __restrict__ bucketTot,
                                                const int* __restrict__ batch,
                                                int* __restrict__ offs,
                                                float* __restrict__ dinv,
                                                int* __restrict__ cnt, int n) {
    __shared__ int a[512], part[256];
    __shared__ int baseS;
    int b = blockIdx.x, t = threadIdx.x;
    int s = 0;
    for (int i = t; i < b; i += 256) s += bucketTot[i];
    part[t] = s;
    __syncthreads();
    for (int off = 128; off > 0; off >>= 1) {
        if (t < off) part[t] += part[t + off];
        __syncthreads();
    }
    if (t == 0) baseS = part[0];
    __syncthreads();
    int base = baseS;
    int v = (b << 8) + t;
    int dg = (v < n) ? deg[v] : 0;
    a[t] = dg; a[t + 256] = 0;
    __syncthreads();
    exscan512(a, part, t);
    if (v < n) {
        offs[v] = base + a[t];
        dinv[v] = rsqrtf((float)(dg + 1));       // +1 = self loop
        atomicAdd(&cnt[batch[v]], 1);
    }
}

// ---- K3c: scatter src into bucket-private adj region ----
__global__ __launch_bounds__(256) void k3c_scatter(const unsigned* __restrict__ sorted,
                                                   const int* __restrict__ histT,
                                                   const int* __restrict__ sstartT,
                                                   const int* __restrict__ offs,
                                                   int* __restrict__ cursor,
                                                   int* __restrict__ adj,
                                                   int B, int nchunks) {
    __shared__ int slen[64], sstart[64], soff[65];
    int b = blockIdx.x, sub = blockIdx.y, t = threadIdx.x;
    int cpg = (nchunks + SUBS - 1) / SUBS;
    int c0 = sub * cpg;
    int c1 = c0 + cpg; if (c1 > nchunks) c1 = nchunks;
    int nc = c1 - c0; if (nc < 0) nc = 0;
    if (t < nc) {
        slen[t]   = histT[(size_t)(c0 + t) * B + b];
        sstart[t] = sstartT[(size_t)(c0 + t) * B + b];
    }
    __syncthreads();
    if (t == 0) {
        int run = 0;
        for (int i2 = 0; i2 < nc; ++i2) { soff[i2] = run; run += slen[i2]; }
        soff[nc] = run;
    }
    __syncthreads();
    int T = soff[nc];
    int vb = b << 8;
    for (int i = t; i < T; i += 256) {
        int lo = 0, hi = nc - 1;
        while (lo < hi) {
            int mid = (lo + hi + 1) >> 1;
            if (soff[mid] <= i) lo = mid; else hi = mid - 1;
        }
        unsigned w = sorted[sstart[lo] + (i - soff[lo])];
        int dst = vb + (int)((w >> 17) & 255);
        int pos = offs[dst] + atomicAdd(&cursor[dst], 1);
        adj[pos] = (int)(w & SRCMASK);
    }
}

// ---- prep: Wt[c][k] = f16(W1[k][c]) ----
__global__ void prep_wt(const float* __restrict__ W, __half* __restrict__ Wt) {
    int t = blockIdx.x * blockDim.x + threadIdx.x;
    int c = t & 127, k = t >> 7;
    Wt[c * 128 + k] = __float2half(W[(size_t)k * 128 + c]);
}

// ---- GEMM1 (MFMA f16): hs1 = (x @ W1) * dinv[row], f16 out ----
__global__ __launch_bounds__(256) void gemm1_mfma(const float* __restrict__ X,
                                                  const __half* __restrict__ Wt,
                                                  const float* __restrict__ dinv,
                                                  __half* __restrict__ out, int n) {
    __shared__ __align__(16) unsigned char As[64 * 128 * 2];
    __shared__ __align__(16) unsigned char Bs[128 * 128 * 2];
    int t = threadIdx.x;
    int wid = t >> 6, lane = t & 63;
    int qw = lane >> 4, lr = lane & 15;
    int rowBase = blockIdx.x * 64;

#pragma unroll
    for (int c = 0; c < 4; ++c) {
        int id = c * 256 + t;
        int r = id >> 4, kc = id & 15;
        int gr = rowBase + r;
        float4 x0, x1;
        if (gr < n) {
            const float4* src = (const float4*)(X + (size_t)gr * 128 + kc * 8);
            x0 = src[0]; x1 = src[1];
        } else {
            x0 = make_float4(0.f, 0.f, 0.f, 0.f); x1 = x0;
        }
        __half2 h0 = __floats2half2_rn(x0.x, x0.y);
        __half2 h1 = __floats2half2_rn(x0.z, x0.w);
        __half2 h2 = __floats2half2_rn(x1.x, x1.y);
        __half2 h3 = __floats2half2_rn(x1.z, x1.w);
        uint4 w;
        w.x = *(unsigned int*)&h0; w.y = *(unsigned int*)&h1;
        w.z = *(unsigned int*)&h2; w.w = *(unsigned int*)&h3;
        int byte = (r * 256 + kc * 16) ^ ((r & 7) << 4);
        *(uint4*)(As + byte) = w;
    }
#pragma unroll
    for (int c = 0; c < 8; ++c) {
        int id = c * 256 + t;
        int cr = id >> 4, kc = id & 15;
        uint4 w = *(const uint4*)(Wt + (size_t)cr * 128 + kc * 8);
        int byte = (cr * 256 + kc * 16) ^ ((cr & 7) << 4);
        *(uint4*)(Bs + byte) = w;
    }
    __syncthreads();

    floatx4 acc[4][2] = {};
#pragma unroll
    for (int ks = 0; ks < 4; ++ks) {
        int kb = ks * 32 + qw * 8;
        half8 a[4], b[2];
#pragma unroll
        for (int m = 0; m < 4; ++m) {
            int row = m * 16 + lr;
            int byte = (row * 256 + kb * 2) ^ ((row & 7) << 4);
            a[m] = *(const half8*)(As + byte);
        }
#pragma unroll
        for (int nn = 0; nn < 2; ++nn) {
            int col = wid * 32 + nn * 16 + lr;
            int byte = (col * 256 + kb * 2) ^ ((col & 7) << 4);
            b[nn] = *(const half8*)(Bs + byte);
        }
#pragma unroll
        for (int m = 0; m < 4; ++m)
#pragma unroll
            for (int nn = 0; nn < 2; ++nn)
                acc[m][nn] = __builtin_amdgcn_mfma_f32_16x16x32_f16(a[m], b[nn], acc[m][nn], 0, 0, 0);
    }

#pragma unroll
    for (int m = 0; m < 4; ++m) {
#pragma unroll
        for (int q = 0; q < 4; ++q) {
            int gr = rowBase + m * 16 + qw * 4 + q;
            if (gr < n) {
                float dv = dinv[gr];
#pragma unroll
                for (int nn = 0; nn < 2; ++nn) {
                    int col = wid * 32 + nn * 16 + lr;
                    out[(size_t)gr * 128 + col] = __float2half(acc[m][nn][q] * dv);
                }
            }
        }
    }
}

// lane holds features [2*lane, 2*lane+1]: one half2 (4B) per lane, 256B row.
__device__ __forceinline__ void acc_h2(unsigned int rv, float2& a) {
    float2 f = __half22float2(*(__half2*)&rv);
    a.x += f.x; a.y += f.y;
}
#define ROWP(buf, u) ((const unsigned int*)((buf) + (size_t)(u) * 128))

// Software-pipelined neighbor sum (r7 verified).
#define PIPE_GATHER(buf)                                                        \
    int nb = d >> 3;                                                            \
    int i = nb << 3;                                                            \
    if (nb > 0) {                                                               \
        int u0 = adj[start+0], u1 = adj[start+1], u2 = adj[start+2],            \
            u3 = adj[start+3], u4 = adj[start+4], u5 = adj[start+5],            \
            u6 = adj[start+6], u7 = adj[start+7];                               \
        unsigned c0 = ROWP(buf,u0)[lane], c1 = ROWP(buf,u1)[lane];              \
        unsigned c2 = ROWP(buf,u2)[lane], c3 = ROWP(buf,u3)[lane];              \
        unsigned c4 = ROWP(buf,u4)[lane], c5 = ROWP(buf,u5)[lane];              \
        unsigned c6 = ROWP(buf,u6)[lane], c7 = ROWP(buf,u7)[lane];              \
        for (int bq = 1; bq < nb; ++bq) {                                       \
            int bs = start + (bq << 3);                                         \
            int t0 = adj[bs+0], t1 = adj[bs+1], t2 = adj[bs+2], t3 = adj[bs+3]; \
            int t4 = adj[bs+4], t5 = adj[bs+5], t6 = adj[bs+6], t7 = adj[bs+7]; \
            unsigned n0 = ROWP(buf,t0)[lane], n1 = ROWP(buf,t1)[lane];          \
            unsigned n2 = ROWP(buf,t2)[lane], n3 = ROWP(buf,t3)[lane];          \
            unsigned n4 = ROWP(buf,t4)[lane], n5 = ROWP(buf,t5)[lane];          \
            unsigned n6 = ROWP(buf,t6)[lane], n7 = ROWP(buf,t7)[lane];          \
            acc_h2(c0, a0); acc_h2(c1, a1); acc_h2(c2, a2); acc_h2(c3, a3);     \
            acc_h2(c4, a0); acc_h2(c5, a1); acc_h2(c6, a2); acc_h2(c7, a3);     \
            c0 = n0; c1 = n1; c2 = n2; c3 = n3;                                 \
            c4 = n4; c5 = n5; c6 = n6; c7 = n7;                                 \
        }                                                                       \
        acc_h2(c0, a0); acc_h2(c1, a1); acc_h2(c2, a2); acc_h2(c3, a3);         \
        acc_h2(c4, a0); acc_h2(c5, a1); acc_h2(c6, a2); acc_h2(c7, a3);         \
    }                                                                           \
    for (; i + 3 < d; i += 4) {                                                 \
        int u0 = adj[start+i+0], u1 = adj[start+i+1];                           \
        int u2 = adj[start+i+2], u3 = adj[start+i+3];                           \
        unsigned r0 = ROWP(buf,u0)[lane], r1 = ROWP(buf,u1)[lane];              \
        unsigned r2 = ROWP(buf,u2)[lane], r3 = ROWP(buf,u3)[lane];              \
        acc_h2(r0, a0); acc_h2(r1, a1); acc_h2(r2, a2); acc_h2(r3, a3);         \
    }                                                                           \
    for (; i < d; ++i) acc_h2(ROWP(buf, adj[start + i])[lane], a0);

// ---- gather1: g1 = relu(dinv*(self+neighbors)+b1); store gs1 = g1*dinv ----
__global__ void gather1(const __half* __restrict__ hs, const int* __restrict__ adj,
                        const int* __restrict__ offs, const int* __restrict__ deg,
                        const float* __restrict__ dinv, const float* __restrict__ b1,
                        __half* __restrict__ gs, int n) {
    int wave = threadIdx.x >> 6;
    int lane = threadIdx.x & 63;
    int v = blockIdx.x * 4 + wave;
    if (v >= n) return;
    float2 a0 = make_float2(0.f, 0.f), a1 = a0, a2 = a0, a3 = a0;
    acc_h2(ROWP(hs, v)[lane], a0);                   // self loop
    int start = __builtin_amdgcn_readfirstlane(offs[v]);
    int d     = __builtin_amdgcn_readfirstlane(deg[v]);
    PIPE_GATHER(hs)
    float accx = (a0.x + a1.x) + (a2.x + a3.x);
    float accy = (a0.y + a1.y) + (a2.y + a3.y);
    float dv = dinv[v];
    float2 bb = ((const float2*)b1)[lane];
    float g0 = fmaxf(accx * dv + bb.x, 0.f) * dv;
    float g1 = fmaxf(accy * dv + bb.y, 0.f) * dv;
    __half2 h = __floats2half2_rn(g0, g1);
    ((unsigned int*)(gs + (size_t)v * 128))[lane] = *(unsigned int*)&h;
}

// ---- gather2 + LDS-pooled mean-pool accumulate ----
__global__ void gather2_pool(const __half* __restrict__ gs, const int* __restrict__ adj,
                             const int* __restrict__ offs, const int* __restrict__ deg,
                             const float* __restrict__ dinv, const int* __restrict__ batch,
                             float* __restrict__ poolsum, int n) {
    __shared__ float poolacc[128];
    int t = threadIdx.x;
    int wave = t >> 6;
    int lane = t & 63;
    if (t < 128) poolacc[t] = 0.f;
    int gref = batch[blockIdx.x * 4];                // first node always < n
    __syncthreads();
    int v = blockIdx.x * 4 + wave;
    if (v < n) {
        float2 a0 = make_float2(0.f, 0.f), a1 = a0, a2 = a0, a3 = a0;
        acc_h2(ROWP(gs, v)[lane], a0);
        int start = __builtin_amdgcn_readfirstlane(offs[v]);
        int d     = __builtin_amdgcn_readfirstlane(deg[v]);
        PIPE_GATHER(gs)
        float accx = (a0.x + a1.x) + (a2.x + a3.x);
        float accy = (a0.y + a1.y) + (a2.y + a3.y);
        float dv = dinv[v];
        int g = batch[v];
        if (g == gref) {
            atomicAdd(&poolacc[lane * 2 + 0], accx * dv);
            atomicAdd(&poolacc[lane * 2 + 1], accy * dv);
        } else {
            float* p = poolsum + (size_t)g * 128;
            atomicAdd(&p[lane * 2 + 0], accx * dv);
            atomicAdd(&p[lane * 2 + 1], accy * dv);
        }
    }
    __syncthreads();
    if (t < 128) {
        float s = poolacc[t];
        if (s != 0.f) atomicAdd(&poolsum[(size_t)gref * 128 + t], s);
    }
}

// ---- head: emb = (pool/cnt) @ W2 + b2 ; logits = emb @ Wg + bg ----
__global__ void head(const float* __restrict__ poolsum, const int* __restrict__ cnt,
                     const float* __restrict__ W2, const float* __restrict__ b2,
                     const float* __restrict__ Wg, const float* __restrict__ bg,
                     float* __restrict__ out, int G) {
    __shared__ float pm[128];
    __shared__ float emb[256];
    int g = blockIdx.x, t = threadIdx.x;
    float inv = 1.f / fmaxf((float)cnt[g], 1.f);
    if (t < 128) pm[t] = poolsum[(size_t)g * 128 + t] * inv;
    __syncthreads();
    float acc = b2[t];
    for (int k = 0; k < 128; ++k) acc += pm[k] * W2[k * 256 + t];
    out[(size_t)g * 256 + t] = acc;
    emb[t] = acc;
    __syncthreads();
    if (t < 16) {
        float a = bg[t];
        for (int j = 0; j < 256; ++j) a += emb[j] * Wg[j * 16 + t];
        out[(size_t)G * 256 + g * 16 + t] = a;
    }
}

extern "C" void kernel_launch(void* const* d_in, const int* in_sizes, int n_in,
                              void* d_out, int out_size, void* d_ws, size_t ws_size,
                              hipStream_t stream) {
    const float* x     = (const float*)d_in[0];
    const int*   ei    = (const int*)d_in[1];
    const int*   batch = (const int*)d_in[2];
    const float* W1    = (const float*)d_in[4];
    const float* b1    = (const float*)d_in[5];
    const float* W2    = (const float*)d_in[6];
    const float* b2    = (const float*)d_in[7];
    const float* Wg    = (const float*)d_in[8];
    const float* bg    = (const float*)d_in[9];
    float* out = (float*)d_out;

    int n = in_sizes[0] / 128;
    int E = in_sizes[1] / 2;
    int G = out_size / (256 + 16);
    int B = (n + 255) >> 8;                 // buckets of 256 nodes (<= 512)
    int nchunks = (E + CHUNK - 1) / CHUNK;  // <= 512

    char* ws = (char*)d_ws;
    auto alloc = [&](size_t bytes) {
        char* p = ws;
        ws += (bytes + 255) & ~(size_t)255;
        return p;
    };
    // ---- zeroed region (contiguous: ONE memset covers all) ----
    char*   zbase     = ws;
    int*    deg       = (int*)alloc((size_t)n * 4);
    int*    cursor    = (int*)alloc((size_t)n * 4);
    int*    bucketTot = (int*)alloc((size_t)(B + 1) * 4);
    int*    cnt       = (int*)alloc((size_t)G * 4);
    float*  poolsum   = (float*)alloc((size_t)G * 128 * 4);
    size_t  zbytes    = (size_t)(ws - zbase);
    // ---- rest ----
    float*    dinv    = (float*)alloc((size_t)n * 4);
    int*      offs    = (int*)alloc((size_t)n * 4);
    int*      adj     = (int*)alloc((size_t)E * 4);
    unsigned* sorted  = (unsigned*)alloc((size_t)E * 4);
    int*      histT   = (int*)alloc((size_t)B * nchunks * 4);
    int*      sstartT = (int*)alloc((size_t)B * nchunks * 4);
    __half*   Wt      = (__half*)alloc(128 * 128 * 2);
    __half*   hs1     = (__half*)alloc((size_t)n * 128 * 2);
    __half*   gs1     = (__half*)alloc((size_t)n * 128 * 2);

    hipMemsetAsync(zbase, 0, zbytes, stream);

    k1_bucket<<<nchunks, 256, 0, stream>>>(ei, E, B, nchunks, sorted, histT, sstartT,
                                           bucketTot, deg);
    k3b_offs<<<B, 256, 0, stream>>>(deg, bucketTot, batch, offs, dinv, cnt, n);
    k3c_scatter<<<dim3(B, SUBS), 256, 0, stream>>>(sorted, histT, sstartT, offs, cursor,
                                                   adj, B, nchunks);

    prep_wt<<<64, TPB, 0, stream>>>(W1, Wt);
    gemm1_mfma<<<(n + 63) / 64, 256, 0, stream>>>(x, Wt, dinv, hs1, n);
    gather1<<<(n + 3) / 4, 256, 0, stream>>>(hs1, adj, offs, deg, dinv, b1, gs1, n);
    gather2_pool<<<(n + 3) / 4, 256, 0, stream>>>(gs1, adj, offs, deg, dinv, batch, poolsum, n);
    head<<<G, 256, 0, stream>>>(poolsum, cnt, W2, b2, Wg, bg, out, G);
}

// Round 11
// 361.258 us; speedup vs baseline: 1.1301x; 1.1301x over previous
//
#include <hip/hip_runtime.h>
#include <hip/hip_fp16.h>

// ---------------------------------------------------------------------------
// ContrastiveGNN: 2-layer GCN + global mean pool + linear head.
//
//   hs1[v]   = (x[v] @ W1) * dinv[v]            (MFMA f16 GEMM, f32 acc, f16 out)
//   g1[v]    = relu(dinv[v]*(hs1[v] + sum_{u->v} hs1[u]) + b1)
//   gs1[v]   = g1[v] * dinv[v]                  (gather1, f32 math, f16 store)
//   a2[v]    = dinv[v]*(gs1[v] + sum_{u->v} gs1[u])
//   pool[g]  = mean_{v in g} a2[v]              (gather2, LDS-pooled atomics)
//   emb      = pool @ W2 + b2 ; logits = emb @ Wg + bg   (tiny head)
//
// Build: k1 bucket-sorts edges into block-private regions (PACKED 4B:
// src | (dst&255)<<17), chunk-major slice tables; k3a counts per-node deg
// from sorted via bucket-private LDS (r10's per-edge GLOBAL deg atomic in k1
// was a 40us regression -- 1.6M random cross-XCD atomics; do not repeat);
// k3b per-bucket scan (computes own base); k3c scatters adj bucket-private.
//
// Gathers (VERIFIED r4/r5/r7): 1 wave/node, lane holds features
// [2*lane, 2*lane+1] (half2), software-pipelined 8-deep.  Gather fetch sits
// at ~2.1 TB/s across all configs (r5-r10) = random-256B-row ceiling;
// structure FROZEN.
// DO NOT reintroduce the half-wave + __shfl restructure (rounds 2/3).
// DO NOT trade wave count for per-wave MLP (r6: conserved concurrency).
// ---------------------------------------------------------------------------

#define TPB 256
#define CHUNK 4096          // edges per K1 block
#define MAXB 512            // max buckets AND max chunks
#define SUBS 8              // sub-blocks per bucket in K3a/K3c
#define SRCMASK 0x1FFFF     // 17 bits: n < 131072

typedef _Float16 half8 __attribute__((ext_vector_type(8)));
typedef float floatx4 __attribute__((ext_vector_type(4)));

// exclusive scan of a[0..512) in LDS, 256 threads; part[255] = total.
__device__ __forceinline__ void exscan512(int* a, int* part, int t) {
    int x0 = a[2 * t], x1 = a[2 * t + 1];
    part[t] = x0 + x1;
    __syncthreads();
    for (int off = 1; off < 256; off <<= 1) {
        int v = (t >= off) ? part[t - off] : 0;
        __syncthreads();
        part[t] += v;
        __syncthreads();
    }
    int base = (t > 0) ? part[t - 1] : 0;
    a[2 * t] = base;
    a[2 * t + 1] = base + x0;
    __syncthreads();
}

// ---- K1: per-chunk bucket sort (bucket = dst>>8), packed 4B ----
__global__ __launch_bounds__(256) void k1_bucket(const int* __restrict__ ei, int E,
                                                 int B, int nchunks,
                                                 unsigned* __restrict__ sorted,
                                                 int* __restrict__ histT,
                                                 int* __restrict__ sstartT,
                                                 int* __restrict__ bucketTot) {
    __shared__ int hcnt[MAXB], hoff[MAXB], hcur[MAXB], part[256];
    int c = blockIdx.x, t = threadIdx.x;
    int e0 = c * CHUNK;
    int m = E - e0; if (m > CHUNK) m = CHUNK;
    for (int i = t; i < MAXB; i += 256) { hcnt[i] = 0; hcur[i] = 0; }
    __syncthreads();
    for (int i = t; i < m; i += 256)
        atomicAdd(&hcnt[ei[E + e0 + i] >> 8], 1);
    __syncthreads();
    for (int i = t; i < MAXB; i += 256) hoff[i] = hcnt[i];
    __syncthreads();
    exscan512(hoff, part, t);
    for (int i = t; i < B; i += 256) {           // chunk-major: coalesced rows
        histT[(size_t)c * B + i]   = hcnt[i];
        sstartT[(size_t)c * B + i] = e0 + hoff[i];
        if (hcnt[i] > 0) atomicAdd(&bucketTot[i], hcnt[i]);
    }
    __syncthreads();
    for (int i = t; i < m; i += 256) {
        int src = ei[e0 + i], dst = ei[E + e0 + i];
        int b = dst >> 8;
        int pos = e0 + hoff[b] + atomicAdd(&hcur[b], 1);
        sorted[pos] = (unsigned)src | ((unsigned)(dst & 255) << 17);
    }
}

// slice-table setup shared by K3a/K3c
#define SLICE_SETUP                                                             \
    int b = blockIdx.x, sub = blockIdx.y, t = threadIdx.x;                      \
    int cpg = (nchunks + SUBS - 1) / SUBS;                                      \
    int c0 = sub * cpg;                                                         \
    int c1 = c0 + cpg; if (c1 > nchunks) c1 = nchunks;                          \
    int nc = c1 - c0; if (nc < 0) nc = 0;                                       \
    if (t < nc) {                                                               \
        slen[t]   = histT[(size_t)(c0 + t) * B + b];                            \
        sstart[t] = sstartT[(size_t)(c0 + t) * B + b];                          \
    }                                                                           \
    __syncthreads();                                                            \
    if (t == 0) {                                                               \
        int run = 0;                                                            \
        for (int i2 = 0; i2 < nc; ++i2) { soff[i2] = run; run += slen[i2]; }    \
        soff[nc] = run;                                                         \
    }                                                                           \
    __syncthreads();                                                            \
    int T = soff[nc];

#define SLICE_EDGE(i)                                                           \
    int lo = 0, hi = nc - 1;                                                    \
    while (lo < hi) { int mid = (lo + hi + 1) >> 1;                             \
                      if (soff[mid] <= (i)) lo = mid; else hi = mid - 1; }      \
    unsigned w = sorted[sstart[lo] + ((i) - soff[lo])];

// ---- K3a: per-node degree (bucket-private LDS count, coalesced flush) ----
__global__ __launch_bounds__(256) void k3a_deg(const unsigned* __restrict__ sorted,
                                               const int* __restrict__ histT,
                                               const int* __restrict__ sstartT,
                                               int* __restrict__ deg,
                                               int n, int B, int nchunks) {
    __shared__ int slen[64], sstart[64], soff[65];
    __shared__ int ncnt[256];
    SLICE_SETUP
    ncnt[t] = 0;
    __syncthreads();
    for (int i = t; i < T; i += 256) {
        SLICE_EDGE(i)
        atomicAdd(&ncnt[(w >> 17) & 255], 1);
    }
    __syncthreads();
    int v = (b << 8) + t;
    if (v < n && ncnt[t] > 0) atomicAdd(&deg[v], ncnt[t]);
}

// ---- K3b: per-bucket scan -> offs/dinv/cnt (computes own bucket base) ----
__global__ __launch_bounds__(256) void k3b_offs(const int* __restrict__ deg,
                                                const int* __restrict__ bucketTot,
                                                const int* __restrict__ batch,
                                                int* __restrict__ offs,
                                                float* __restrict__ dinv,
                                                int* __restrict__ cnt, int n) {
    __shared__ int a[512], part[256];
    __shared__ int baseS;
    int b = blockIdx.x, t = threadIdx.x;
    int s = 0;
    for (int i = t; i < b; i += 256) s += bucketTot[i];
    part[t] = s;
    __syncthreads();
    for (int off = 128; off > 0; off >>= 1) {
        if (t < off) part[t] += part[t + off];
        __syncthreads();
    }
    if (t == 0) baseS = part[0];
    __syncthreads();
    int base = baseS;
    int v = (b << 8) + t;
    int dg = (v < n) ? deg[v] : 0;
    a[t] = dg; a[t + 256] = 0;
    __syncthreads();
    exscan512(a, part, t);
    if (v < n) {
        offs[v] = base + a[t];
        dinv[v] = rsqrtf((float)(dg + 1));       // +1 = self loop
        atomicAdd(&cnt[batch[v]], 1);
    }
}

// ---- K3c: scatter src into bucket-private adj region ----
__global__ __launch_bounds__(256) void k3c_scatter(const unsigned* __restrict__ sorted,
                                                   const int* __restrict__ histT,
                                                   const int* __restrict__ sstartT,
                                                   const int* __restrict__ offs,
                                                   int* __restrict__ cursor,
                                                   int* __restrict__ adj,
                                                   int B, int nchunks) {
    __shared__ int slen[64], sstart[64], soff[65];
    SLICE_SETUP
    int vb = b << 8;
    for (int i = t; i < T; i += 256) {
        SLICE_EDGE(i)
        int dst = vb + (int)((w >> 17) & 255);
        int pos = offs[dst] + atomicAdd(&cursor[dst], 1);
        adj[pos] = (int)(w & SRCMASK);
    }
}

// ---- prep: Wt[c][k] = f16(W1[k][c]) ----
__global__ void prep_wt(const float* __restrict__ W, __half* __restrict__ Wt) {
    int t = blockIdx.x * blockDim.x + threadIdx.x;
    int c = t & 127, k = t >> 7;
    Wt[c * 128 + k] = __float2half(W[(size_t)k * 128 + c]);
}

// ---- GEMM1 (MFMA f16): hs1 = (x @ W1) * dinv[row], f16 out ----
__global__ __launch_bounds__(256) void gemm1_mfma(const float* __restrict__ X,
                                                  const __half* __restrict__ Wt,
                                                  const float* __restrict__ dinv,
                                                  __half* __restrict__ out, int n) {
    __shared__ __align__(16) unsigned char As[64 * 128 * 2];
    __shared__ __align__(16) unsigned char Bs[128 * 128 * 2];
    int t = threadIdx.x;
    int wid = t >> 6, lane = t & 63;
    int qw = lane >> 4, lr = lane & 15;
    int rowBase = blockIdx.x * 64;

#pragma unroll
    for (int c = 0; c < 4; ++c) {
        int id = c * 256 + t;
        int r = id >> 4, kc = id & 15;
        int gr = rowBase + r;
        float4 x0, x1;
        if (gr < n) {
            const float4* src = (const float4*)(X + (size_t)gr * 128 + kc * 8);
            x0 = src[0]; x1 = src[1];
        } else {
            x0 = make_float4(0.f, 0.f, 0.f, 0.f); x1 = x0;
        }
        __half2 h0 = __floats2half2_rn(x0.x, x0.y);
        __half2 h1 = __floats2half2_rn(x0.z, x0.w);
        __half2 h2 = __floats2half2_rn(x1.x, x1.y);
        __half2 h3 = __floats2half2_rn(x1.z, x1.w);
        uint4 w;
        w.x = *(unsigned int*)&h0; w.y = *(unsigned int*)&h1;
        w.z = *(unsigned int*)&h2; w.w = *(unsigned int*)&h3;
        int byte = (r * 256 + kc * 16) ^ ((r & 7) << 4);
        *(uint4*)(As + byte) = w;
    }
#pragma unroll
    for (int c = 0; c < 8; ++c) {
        int id = c * 256 + t;
        int cr = id >> 4, kc = id & 15;
        uint4 w = *(const uint4*)(Wt + (size_t)cr * 128 + kc * 8);
        int byte = (cr * 256 + kc * 16) ^ ((cr & 7) << 4);
        *(uint4*)(Bs + byte) = w;
    }
    __syncthreads();

    floatx4 acc[4][2] = {};
#pragma unroll
    for (int ks = 0; ks < 4; ++ks) {
        int kb = ks * 32 + qw * 8;
        half8 a[4], b[2];
#pragma unroll
        for (int m = 0; m < 4; ++m) {
            int row = m * 16 + lr;
            int byte = (row * 256 + kb * 2) ^ ((row & 7) << 4);
            a[m] = *(const half8*)(As + byte);
        }
#pragma unroll
        for (int nn = 0; nn < 2; ++nn) {
            int col = wid * 32 + nn * 16 + lr;
            int byte = (col * 256 + kb * 2) ^ ((col & 7) << 4);
            b[nn] = *(const half8*)(Bs + byte);
        }
#pragma unroll
        for (int m = 0; m < 4; ++m)
#pragma unroll
            for (int nn = 0; nn < 2; ++nn)
                acc[m][nn] = __builtin_amdgcn_mfma_f32_16x16x32_f16(a[m], b[nn], acc[m][nn], 0, 0, 0);
    }

#pragma unroll
    for (int m = 0; m < 4; ++m) {
#pragma unroll
        for (int q = 0; q < 4; ++q) {
            int gr = rowBase + m * 16 + qw * 4 + q;
            if (gr < n) {
                float dv = dinv[gr];
#pragma unroll
                for (int nn = 0; nn < 2; ++nn) {
                    int col = wid * 32 + nn * 16 + lr;
                    out[(size_t)gr * 128 + col] = __float2half(acc[m][nn][q] * dv);
                }
            }
        }
    }
}

// lane holds features [2*lane, 2*lane+1]: one half2 (4B) per lane, 256B row.
__device__ __forceinline__ void acc_h2(unsigned int rv, float2& a) {
    float2 f = __half22float2(*(__half2*)&rv);
    a.x += f.x; a.y += f.y;
}
#define ROWP(buf, u) ((const unsigned int*)((buf) + (size_t)(u) * 128))

// Software-pipelined neighbor sum (r7 verified).
#define PIPE_GATHER(buf)                                                        \
    int nb = d >> 3;                                                            \
    int i = nb << 3;                                                            \
    if (nb > 0) {                                                               \
        int u0 = adj[start+0], u1 = adj[start+1], u2 = adj[start+2],            \
            u3 = adj[start+3], u4 = adj[start+4], u5 = adj[start+5],            \
            u6 = adj[start+6], u7 = adj[start+7];                               \
        unsigned c0 = ROWP(buf,u0)[lane], c1 = ROWP(buf,u1)[lane];              \
        unsigned c2 = ROWP(buf,u2)[lane], c3 = ROWP(buf,u3)[lane];              \
        unsigned c4 = ROWP(buf,u4)[lane], c5 = ROWP(buf,u5)[lane];              \
        unsigned c6 = ROWP(buf,u6)[lane], c7 = ROWP(buf,u7)[lane];              \
        for (int bq = 1; bq < nb; ++bq) {                                       \
            int bs = start + (bq << 3);                                         \
            int t0 = adj[bs+0], t1 = adj[bs+1], t2 = adj[bs+2], t3 = adj[bs+3]; \
            int t4 = adj[bs+4], t5 = adj[bs+5], t6 = adj[bs+6], t7 = adj[bs+7]; \
            unsigned n0 = ROWP(buf,t0)[lane], n1 = ROWP(buf,t1)[lane];          \
            unsigned n2 = ROWP(buf,t2)[lane], n3 = ROWP(buf,t3)[lane];          \
            unsigned n4 = ROWP(buf,t4)[lane], n5 = ROWP(buf,t5)[lane];          \
            unsigned n6 = ROWP(buf,t6)[lane], n7 = ROWP(buf,t7)[lane];          \
            acc_h2(c0, a0); acc_h2(c1, a1); acc_h2(c2, a2); acc_h2(c3, a3);     \
            acc_h2(c4, a0); acc_h2(c5, a1); acc_h2(c6, a2); acc_h2(c7, a3);     \
            c0 = n0; c1 = n1; c2 = n2; c3 = n3;                                 \
            c4 = n4; c5 = n5; c6 = n6; c7 = n7;                                 \
        }                                                                       \
        acc_h2(c0, a0); acc_h2(c1, a1); acc_h2(c2, a2); acc_h2(c3, a3);         \
        acc_h2(c4, a0); acc_h2(c5, a1); acc_h2(c6, a2); acc_h2(c7, a3);         \
    }                                                                           \
    for (; i + 3 < d; i += 4) {                                                 \
        int u0 = adj[start+i+0], u1 = adj[start+i+1];                           \
        int u2 = adj[start+i+2], u3 = adj[start+i+3];                           \
        unsigned r0 = ROWP(buf,u0)[lane], r1 = ROWP(buf,u1)[lane];              \
        unsigned r2 = ROWP(buf,u2)[lane], r3 = ROWP(buf,u3)[lane];              \
        acc_h2(r0, a0); acc_h2(r1, a1); acc_h2(r2, a2); acc_h2(r3, a3);         \
    }                                                                           \
    for (; i < d; ++i) acc_h2(ROWP(buf, adj[start + i])[lane], a0);

// ---- gather1: g1 = relu(dinv*(self+neighbors)+b1); store gs1 = g1*dinv ----
__global__ void gather1(const __half* __restrict__ hs, const int* __restrict__ adj,
                        const int* __restrict__ offs, const int* __restrict__ deg,
                        const float* __restrict__ dinv, const float* __restrict__ b1,
                        __half* __restrict__ gs, int n) {
    int wave = threadIdx.x >> 6;
    int lane = threadIdx.x & 63;
    int v = blockIdx.x * 4 + wave;
    if (v >= n) return;
    float2 a0 = make_float2(0.f, 0.f), a1 = a0, a2 = a0, a3 = a0;
    acc_h2(ROWP(hs, v)[lane], a0);                   // self loop
    int start = __builtin_amdgcn_readfirstlane(offs[v]);
    int d     = __builtin_amdgcn_readfirstlane(deg[v]);
    PIPE_GATHER(hs)
    float accx = (a0.x + a1.x) + (a2.x + a3.x);
    float accy = (a0.y + a1.y) + (a2.y + a3.y);
    float dv = dinv[v];
    float2 bb = ((const float2*)b1)[lane];
    float g0 = fmaxf(accx * dv + bb.x, 0.f) * dv;
    float g1 = fmaxf(accy * dv + bb.y, 0.f) * dv;
    __half2 h = __floats2half2_rn(g0, g1);
    ((unsigned int*)(gs + (size_t)v * 128))[lane] = *(unsigned int*)&h;
}

// ---- gather2 + LDS-pooled mean-pool accumulate ----
__global__ void gather2_pool(const __half* __restrict__ gs, const int* __restrict__ adj,
                             const int* __restrict__ offs, const int* __restrict__ deg,
                             const float* __restrict__ dinv, const int* __restrict__ batch,
                             float* __restrict__ poolsum, int n) {
    __shared__ float poolacc[128];
    int t = threadIdx.x;
    int wave = t >> 6;
    int lane = t & 63;
    if (t < 128) poolacc[t] = 0.f;
    int gref = batch[blockIdx.x * 4];                // first node always < n
    __syncthreads();
    int v = blockIdx.x * 4 + wave;
    if (v < n) {
        float2 a0 = make_float2(0.f, 0.f), a1 = a0, a2 = a0, a3 = a0;
        acc_h2(ROWP(gs, v)[lane], a0);
        int start = __builtin_amdgcn_readfirstlane(offs[v]);
        int d     = __builtin_amdgcn_readfirstlane(deg[v]);
        PIPE_GATHER(gs)
        float accx = (a0.x + a1.x) + (a2.x + a3.x);
        float accy = (a0.y + a1.y) + (a2.y + a3.y);
        float dv = dinv[v];
        int g = batch[v];
        if (g == gref) {
            atomicAdd(&poolacc[lane * 2 + 0], accx * dv);
            atomicAdd(&poolacc[lane * 2 + 1], accy * dv);
        } else {
            float* p = poolsum + (size_t)g * 128;
            atomicAdd(&p[lane * 2 + 0], accx * dv);
            atomicAdd(&p[lane * 2 + 1], accy * dv);
        }
    }
    __syncthreads();
    if (t < 128) {
        float s = poolacc[t];
        if (s != 0.f) atomicAdd(&poolsum[(size_t)gref * 128 + t], s);
    }
}

// ---- head: emb = (pool/cnt) @ W2 + b2 ; logits = emb @ Wg + bg ----
__global__ void head(const float* __restrict__ poolsum, const int* __restrict__ cnt,
                     const float* __restrict__ W2, const float* __restrict__ b2,
                     const float* __restrict__ Wg, const float* __restrict__ bg,
                     float* __restrict__ out, int G) {
    __shared__ float pm[128];
    __shared__ float emb[256];
    int g = blockIdx.x, t = threadIdx.x;
    float inv = 1.f / fmaxf((float)cnt[g], 1.f);
    if (t < 128) pm[t] = poolsum[(size_t)g * 128 + t] * inv;
    __syncthreads();
    float acc = b2[t];
    for (int k = 0; k < 128; ++k) acc += pm[k] * W2[k * 256 + t];
    out[(size_t)g * 256 + t] = acc;
    emb[t] = acc;
    __syncthreads();
    if (t < 16) {
        float a = bg[t];
        for (int j = 0; j < 256; ++j) a += emb[j] * Wg[j * 16 + t];
        out[(size_t)G * 256 + g * 16 + t] = a;
    }
}

extern "C" void kernel_launch(void* const* d_in, const int* in_sizes, int n_in,
                              void* d_out, int out_size, void* d_ws, size_t ws_size,
                              hipStream_t stream) {
    const float* x     = (const float*)d_in[0];
    const int*   ei    = (const int*)d_in[1];
    const int*   batch = (const int*)d_in[2];
    const float* W1    = (const float*)d_in[4];
    const float* b1    = (const float*)d_in[5];
    const float* W2    = (const float*)d_in[6];
    const float* b2    = (const float*)d_in[7];
    const float* Wg    = (const float*)d_in[8];
    const float* bg    = (const float*)d_in[9];
    float* out = (float*)d_out;

    int n = in_sizes[0] / 128;
    int E = in_sizes[1] / 2;
    int G = out_size / (256 + 16);
    int B = (n + 255) >> 8;                 // buckets of 256 nodes (<= 512)
    int nchunks = (E + CHUNK - 1) / CHUNK;  // <= 512

    char* ws = (char*)d_ws;
    auto alloc = [&](size_t bytes) {
        char* p = ws;
        ws += (bytes + 255) & ~(size_t)255;
        return p;
    };
    // ---- zeroed region (contiguous: ONE memset covers all) ----
    char*   zbase     = ws;
    int*    deg       = (int*)alloc((size_t)n * 4);
    int*    cursor    = (int*)alloc((size_t)n * 4);
    int*    bucketTot = (int*)alloc((size_t)(B + 1) * 4);
    int*    cnt       = (int*)alloc((size_t)G * 4);
    float*  poolsum   = (float*)alloc((size_t)G * 128 * 4);
    size_t  zbytes    = (size_t)(ws - zbase);
    // ---- rest ----
    float*    dinv    = (float*)alloc((size_t)n * 4);
    int*      offs    = (int*)alloc((size_t)n * 4);
    int*      adj     = (int*)alloc((size_t)E * 4);
    unsigned* sorted  = (unsigned*)alloc((size_t)E * 4);
    int*      histT   = (int*)alloc((size_t)B * nchunks * 4);
    int*      sstartT = (int*)alloc((size_t)B * nchunks * 4);
    __half*   Wt      = (__half*)alloc(128 * 128 * 2);
    __half*   hs1     = (__half*)alloc((size_t)n * 128 * 2);
    __half*   gs1     = (__half*)alloc((size_t)n * 128 * 2);

    hipMemsetAsync(zbase, 0, zbytes, stream);

    k1_bucket<<<nchunks, 256, 0, stream>>>(ei, E, B, nchunks, sorted, histT, sstartT,
                                           bucketTot);
    k3a_deg<<<dim3(B, SUBS), 256, 0, stream>>>(sorted, histT, sstartT, deg, n, B, nchunks);
    k3b_offs<<<B, 256, 0, stream>>>(deg, bucketTot, batch, offs, dinv, cnt, n);
    k3c_scatter<<<dim3(B, SUBS), 256, 0, stream>>>(sorted, histT, sstartT, offs, cursor,
                                                   adj, B, nchunks);

    prep_wt<<<64, TPB, 0, stream>>>(W1, Wt);
    gemm1_mfma<<<(n + 63) / 64, 256, 0, stream>>>(x, Wt, dinv, hs1, n);
    gather1<<<(n + 3) / 4, 256, 0, stream>>>(hs1, adj, offs, deg, dinv, b1, gs1, n);
    gather2_pool<<<(n + 3) / 4, 256, 0, stream>>>(gs1, adj, offs, deg, dinv, batch, poolsum, n);
    head<<<G, 256, 0, stream>>>(poolsum, cnt, W2, b2, Wg, bg, out, G);
}

// Round 12
// 340.392 us; speedup vs baseline: 1.1994x; 1.0613x over previous
//
#include <hip/hip_runtime.h>
#include <hip/hip_fp16.h>

// ---------------------------------------------------------------------------
// ContrastiveGNN: 2-layer GCN + global mean pool + linear head.
//
//   hs1[v]   = (x[v] @ W1) * dinv[v]            (MFMA f16 GEMM, f32 acc, f16 out)
//   g1[v]    = relu(dinv[v]*(hs1[v] + sum_{u->v} hs1[u]) + b1)
//   gs1[v]   = g1[v] * dinv[v]                  (gather1, f32 math, f16 store)
//   a2[v]    = dinv[v]*(gs1[v] + sum_{u->v} gs1[u])
//   pool[g]  = mean_{v in g} a2[v]              (gather2, LDS-pooled atomics)
//   emb      = pool @ W2 + b2 ; logits = emb @ Wg + bg   (tiny head)
//
// Build (r12, zero global atomics in k3):
//   k1  : chunk bucket-sort, packed 4B (src | (dst&255)<<17), chunk-major tables
//   k3a : per-(bucket,sub) slice -> LDS count -> degSub[sub][v] plain write
//   k3b : deg = sum_s degSub, scan -> offs/dinv/cnt; degSub[s][v] overwritten
//         with absolute scatter base for (v,s)
//   k3c : LDS cursor from degSub[sub], scatter adj with LDS atomics only
// r10 lesson: per-edge GLOBAL atomics on node arrays = cross-XCD RMW ping-pong
// (40us regression); k3c's global cursor was the last instance -- now gone.
//
// Gathers (VERIFIED r4/r5/r7, FROZEN): 1 wave/node, lane holds features
// [2*lane, 2*lane+1] (half2), software-pipelined 8-deep.  FETCH ~196MB =
// 8 XCDs x 25.6MB table = random-gather replication floor; ~2 TB/s pattern
// ceiling invariant across r5-r11.
// DO NOT reintroduce the half-wave + __shfl restructure (rounds 2/3).
// DO NOT trade wave count for per-wave MLP (r6: conserved concurrency).
// ---------------------------------------------------------------------------

#define TPB 256
#define CHUNK 4096          // edges per K1 block
#define MAXB 512            // max buckets AND max chunks
#define SUBS 8              // sub-blocks per bucket in K3a/K3c
#define SRCMASK 0x1FFFF     // 17 bits: n < 131072

typedef _Float16 half8 __attribute__((ext_vector_type(8)));
typedef float floatx4 __attribute__((ext_vector_type(4)));

// exclusive scan of a[0..512) in LDS, 256 threads; part[255] = total.
__device__ __forceinline__ void exscan512(int* a, int* part, int t) {
    int x0 = a[2 * t], x1 = a[2 * t + 1];
    part[t] = x0 + x1;
    __syncthreads();
    for (int off = 1; off < 256; off <<= 1) {
        int v = (t >= off) ? part[t - off] : 0;
        __syncthreads();
        part[t] += v;
        __syncthreads();
    }
    int base = (t > 0) ? part[t - 1] : 0;
    a[2 * t] = base;
    a[2 * t + 1] = base + x0;
    __syncthreads();
}

// ---- K1: per-chunk bucket sort (bucket = dst>>8), packed 4B ----
__global__ __launch_bounds__(256) void k1_bucket(const int* __restrict__ ei, int E,
                                                 int B, int nchunks,
                                                 unsigned* __restrict__ sorted,
                                                 int* __restrict__ histT,
                                                 int* __restrict__ sstartT,
                                                 int* __restrict__ bucketTot) {
    __shared__ int hcnt[MAXB], hoff[MAXB], hcur[MAXB], part[256];
    int c = blockIdx.x, t = threadIdx.x;
    int e0 = c * CHUNK;
    int m = E - e0; if (m > CHUNK) m = CHUNK;
    for (int i = t; i < MAXB; i += 256) { hcnt[i] = 0; hcur[i] = 0; }
    __syncthreads();
    for (int i = t; i < m; i += 256)
        atomicAdd(&hcnt[ei[E + e0 + i] >> 8], 1);
    __syncthreads();
    for (int i = t; i < MAXB; i += 256) hoff[i] = hcnt[i];
    __syncthreads();
    exscan512(hoff, part, t);
    for (int i = t; i < B; i += 256) {           // chunk-major: coalesced rows
        histT[(size_t)c * B + i]   = hcnt[i];
        sstartT[(size_t)c * B + i] = e0 + hoff[i];
        if (hcnt[i] > 0) atomicAdd(&bucketTot[i], hcnt[i]);
    }
    __syncthreads();
    for (int i = t; i < m; i += 256) {
        int src = ei[e0 + i], dst = ei[E + e0 + i];
        int b = dst >> 8;
        int pos = e0 + hoff[b] + atomicAdd(&hcur[b], 1);
        sorted[pos] = (unsigned)src | ((unsigned)(dst & 255) << 17);
    }
}

// slice-table setup shared by K3a/K3c
#define SLICE_SETUP                                                             \
    int b = blockIdx.x, sub = blockIdx.y, t = threadIdx.x;                      \
    int cpg = (nchunks + SUBS - 1) / SUBS;                                      \
    int c0 = sub * cpg;                                                         \
    int c1 = c0 + cpg; if (c1 > nchunks) c1 = nchunks;                          \
    int nc = c1 - c0; if (nc < 0) nc = 0;                                       \
    if (t < nc) {                                                               \
        slen[t]   = histT[(size_t)(c0 + t) * B + b];                            \
        sstart[t] = sstartT[(size_t)(c0 + t) * B + b];                          \
    }                                                                           \
    __syncthreads();                                                            \
    if (t == 0) {                                                               \
        int run = 0;                                                            \
        for (int i2 = 0; i2 < nc; ++i2) { soff[i2] = run; run += slen[i2]; }    \
        soff[nc] = run;                                                         \
    }                                                                           \
    __syncthreads();                                                            \
    int T = soff[nc];

#define SLICE_EDGE(i)                                                           \
    int lo = 0, hi = nc - 1;                                                    \
    while (lo < hi) { int mid = (lo + hi + 1) >> 1;                             \
                      if (soff[mid] <= (i)) lo = mid; else hi = mid - 1; }      \
    unsigned w = sorted[sstart[lo] + ((i) - soff[lo])];

// ---- K3a: per-(bucket,sub) degree -> degSub[sub][v], NO global atomics ----
__global__ __launch_bounds__(256) void k3a_deg(const unsigned* __restrict__ sorted,
                                               const int* __restrict__ histT,
                                               const int* __restrict__ sstartT,
                                               int* __restrict__ degSub,
                                               int B, int nchunks) {
    __shared__ int slen[64], sstart[64], soff[65];
    __shared__ int ncnt[256];
    SLICE_SETUP
    ncnt[t] = 0;
    __syncthreads();
    for (int i = t; i < T; i += 256) {
        SLICE_EDGE(i)
        atomicAdd(&ncnt[(w >> 17) & 255], 1);
    }
    __syncthreads();
    degSub[(size_t)sub * (B << 8) + (b << 8) + t] = ncnt[t];   // plain write
}

// ---- K3b: deg = sum_s degSub; scan -> offs/dinv/cnt; degSub -> sub bases ----
__global__ __launch_bounds__(256) void k3b_offs(int* __restrict__ degSub,
                                                const int* __restrict__ bucketTot,
                                                const int* __restrict__ batch,
                                                int* __restrict__ offs,
                                                int* __restrict__ deg,
                                                float* __restrict__ dinv,
                                                int* __restrict__ cnt, int n, int B) {
    __shared__ int a[512], part[256];
    __shared__ int baseS;
    int b = blockIdx.x, t = threadIdx.x;
    int s = 0;
    for (int i = t; i < b; i += 256) s += bucketTot[i];
    part[t] = s;
    __syncthreads();
    for (int off = 128; off > 0; off >>= 1) {
        if (t < off) part[t] += part[t + off];
        __syncthreads();
    }
    if (t == 0) baseS = part[0];
    __syncthreads();
    int base = baseS;
    size_t stride = (size_t)(B << 8);
    size_t vi = (size_t)(b << 8) + t;
    int ds[SUBS];
    int dg = 0;
#pragma unroll
    for (int q = 0; q < SUBS; ++q) { ds[q] = degSub[q * stride + vi]; dg += ds[q]; }
    a[t] = dg; a[t + 256] = 0;
    __syncthreads();
    exscan512(a, part, t);
    int v = (b << 8) + t;
    int vbase = base + a[t];
    // overwrite degSub[s][v] with absolute scatter base for (v, s)
    int run = vbase;
#pragma unroll
    for (int q = 0; q < SUBS; ++q) { int c = ds[q]; degSub[q * stride + vi] = run; run += c; }
    if (v < n) {
        offs[v] = vbase;
        deg[v]  = dg;
        dinv[v] = rsqrtf((float)(dg + 1));       // +1 = self loop
        atomicAdd(&cnt[batch[v]], 1);
    }
}

// ---- K3c: scatter src via LDS cursor (zero global atomics) ----
__global__ __launch_bounds__(256) void k3c_scatter(const unsigned* __restrict__ sorted,
                                                   const int* __restrict__ histT,
                                                   const int* __restrict__ sstartT,
                                                   const int* __restrict__ degSub,
                                                   int* __restrict__ adj,
                                                   int B, int nchunks) {
    __shared__ int slen[64], sstart[64], soff[65];
    __shared__ int cur[256];
    SLICE_SETUP
    cur[t] = degSub[(size_t)sub * (B << 8) + (b << 8) + t];
    __syncthreads();
    for (int i = t; i < T; i += 256) {
        SLICE_EDGE(i)
        int r = (w >> 17) & 255;
        int pos = atomicAdd(&cur[r], 1);         // LDS atomic only
        adj[pos] = (int)(w & SRCMASK);
    }
}

// ---- prep: Wt[c][k] = f16(W1[k][c]) ----
__global__ void prep_wt(const float* __restrict__ W, __half* __restrict__ Wt) {
    int t = blockIdx.x * blockDim.x + threadIdx.x;
    int c = t & 127, k = t >> 7;
    Wt[c * 128 + k] = __float2half(W[(size_t)k * 128 + c]);
}

// ---- GEMM1 (MFMA f16): hs1 = (x @ W1) * dinv[row], f16 out ----
__global__ __launch_bounds__(256) void gemm1_mfma(const float* __restrict__ X,
                                                  const __half* __restrict__ Wt,
                                                  const float* __restrict__ dinv,
                                                  __half* __restrict__ out, int n) {
    __shared__ __align__(16) unsigned char As[64 * 128 * 2];
    __shared__ __align__(16) unsigned char Bs[128 * 128 * 2];
    int t = threadIdx.x;
    int wid = t >> 6, lane = t & 63;
    int qw = lane >> 4, lr = lane & 15;
    int rowBase = blockIdx.x * 64;

#pragma unroll
    for (int c = 0; c < 4; ++c) {
        int id = c * 256 + t;
        int r = id >> 4, kc = id & 15;
        int gr = rowBase + r;
        float4 x0, x1;
        if (gr < n) {
            const float4* src = (const float4*)(X + (size_t)gr * 128 + kc * 8);
            x0 = src[0]; x1 = src[1];
        } else {
            x0 = make_float4(0.f, 0.f, 0.f, 0.f); x1 = x0;
        }
        __half2 h0 = __floats2half2_rn(x0.x, x0.y);
        __half2 h1 = __floats2half2_rn(x0.z, x0.w);
        __half2 h2 = __floats2half2_rn(x1.x, x1.y);
        __half2 h3 = __floats2half2_rn(x1.z, x1.w);
        uint4 w;
        w.x = *(unsigned int*)&h0; w.y = *(unsigned int*)&h1;
        w.z = *(unsigned int*)&h2; w.w = *(unsigned int*)&h3;
        int byte = (r * 256 + kc * 16) ^ ((r & 7) << 4);
        *(uint4*)(As + byte) = w;
    }
#pragma unroll
    for (int c = 0; c < 8; ++c) {
        int id = c * 256 + t;
        int cr = id >> 4, kc = id & 15;
        uint4 w = *(const uint4*)(Wt + (size_t)cr * 128 + kc * 8);
        int byte = (cr * 256 + kc * 16) ^ ((cr & 7) << 4);
        *(uint4*)(Bs + byte) = w;
    }
    __syncthreads();

    floatx4 acc[4][2] = {};
#pragma unroll
    for (int ks = 0; ks < 4; ++ks) {
        int kb = ks * 32 + qw * 8;
        half8 a[4], b[2];
#pragma unroll
        for (int m = 0; m < 4; ++m) {
            int row = m * 16 + lr;
            int byte = (row * 256 + kb * 2) ^ ((row & 7) << 4);
            a[m] = *(const half8*)(As + byte);
        }
#pragma unroll
        for (int nn = 0; nn < 2; ++nn) {
            int col = wid * 32 + nn * 16 + lr;
            int byte = (col * 256 + kb * 2) ^ ((col & 7) << 4);
            b[nn] = *(const half8*)(Bs + byte);
        }
#pragma unroll
        for (int m = 0; m < 4; ++m)
#pragma unroll
            for (int nn = 0; nn < 2; ++nn)
                acc[m][nn] = __builtin_amdgcn_mfma_f32_16x16x32_f16(a[m], b[nn], acc[m][nn], 0, 0, 0);
    }

#pragma unroll
    for (int m = 0; m < 4; ++m) {
#pragma unroll
        for (int q = 0; q < 4; ++q) {
            int gr = rowBase + m * 16 + qw * 4 + q;
            if (gr < n) {
                float dv = dinv[gr];
#pragma unroll
                for (int nn = 0; nn < 2; ++nn) {
                    int col = wid * 32 + nn * 16 + lr;
                    out[(size_t)gr * 128 + col] = __float2half(acc[m][nn][q] * dv);
                }
            }
        }
    }
}

// lane holds features [2*lane, 2*lane+1]: one half2 (4B) per lane, 256B row.
__device__ __forceinline__ void acc_h2(unsigned int rv, float2& a) {
    float2 f = __half22float2(*(__half2*)&rv);
    a.x += f.x; a.y += f.y;
}
#define ROWP(buf, u) ((const unsigned int*)((buf) + (size_t)(u) * 128))

// Software-pipelined neighbor sum (r7 verified).
#define PIPE_GATHER(buf)                                                        \
    int nb = d >> 3;                                                            \
    int i = nb << 3;                                                            \
    if (nb > 0) {                                                               \
        int u0 = adj[start+0], u1 = adj[start+1], u2 = adj[start+2],            \
            u3 = adj[start+3], u4 = adj[start+4], u5 = adj[start+5],            \
            u6 = adj[start+6], u7 = adj[start+7];                               \
        unsigned c0 = ROWP(buf,u0)[lane], c1 = ROWP(buf,u1)[lane];              \
        unsigned c2 = ROWP(buf,u2)[lane], c3 = ROWP(buf,u3)[lane];              \
        unsigned c4 = ROWP(buf,u4)[lane], c5 = ROWP(buf,u5)[lane];              \
        unsigned c6 = ROWP(buf,u6)[lane], c7 = ROWP(buf,u7)[lane];              \
        for (int bq = 1; bq < nb; ++bq) {                                       \
            int bs = start + (bq << 3);                                         \
            int t0 = adj[bs+0], t1 = adj[bs+1], t2 = adj[bs+2], t3 = adj[bs+3]; \
            int t4 = adj[bs+4], t5 = adj[bs+5], t6 = adj[bs+6], t7 = adj[bs+7]; \
            unsigned n0 = ROWP(buf,t0)[lane], n1 = ROWP(buf,t1)[lane];          \
            unsigned n2 = ROWP(buf,t2)[lane], n3 = ROWP(buf,t3)[lane];          \
            unsigned n4 = ROWP(buf,t4)[lane], n5 = ROWP(buf,t5)[lane];          \
            unsigned n6 = ROWP(buf,t6)[lane], n7 = ROWP(buf,t7)[lane];          \
            acc_h2(c0, a0); acc_h2(c1, a1); acc_h2(c2, a2); acc_h2(c3, a3);     \
            acc_h2(c4, a0); acc_h2(c5, a1); acc_h2(c6, a2); acc_h2(c7, a3);     \
            c0 = n0; c1 = n1; c2 = n2; c3 = n3;                                 \
            c4 = n4; c5 = n5; c6 = n6; c7 = n7;                                 \
        }                                                                       \
        acc_h2(c0, a0); acc_h2(c1, a1); acc_h2(c2, a2); acc_h2(c3, a3);         \
        acc_h2(c4, a0); acc_h2(c5, a1); acc_h2(c6, a2); acc_h2(c7, a3);         \
    }                                                                           \
    for (; i + 3 < d; i += 4) {                                                 \
        int u0 = adj[start+i+0], u1 = adj[start+i+1];                           \
        int u2 = adj[start+i+2], u3 = adj[start+i+3];                           \
        unsigned r0 = ROWP(buf,u0)[lane], r1 = ROWP(buf,u1)[lane];              \
        unsigned r2 = ROWP(buf,u2)[lane], r3 = ROWP(buf,u3)[lane];              \
        acc_h2(r0, a0); acc_h2(r1, a1); acc_h2(r2, a2); acc_h2(r3, a3);         \
    }                                                                           \
    for (; i < d; ++i) acc_h2(ROWP(buf, adj[start + i])[lane], a0);

// ---- gather1: g1 = relu(dinv*(self+neighbors)+b1); store gs1 = g1*dinv ----
__global__ void gather1(const __half* __restrict__ hs, const int* __restrict__ adj,
                        const int* __restrict__ offs, const int* __restrict__ deg,
                        const float* __restrict__ dinv, const float* __restrict__ b1,
                        __half* __restrict__ gs, int n) {
    int wave = threadIdx.x >> 6;
    int lane = threadIdx.x & 63;
    int v = blockIdx.x * 4 + wave;
    if (v >= n) return;
    float2 a0 = make_float2(0.f, 0.f), a1 = a0, a2 = a0, a3 = a0;
    acc_h2(ROWP(hs, v)[lane], a0);                   // self loop
    int start = __builtin_amdgcn_readfirstlane(offs[v]);
    int d     = __builtin_amdgcn_readfirstlane(deg[v]);
    PIPE_GATHER(hs)
    float accx = (a0.x + a1.x) + (a2.x + a3.x);
    float accy = (a0.y + a1.y) + (a2.y + a3.y);
    float dv = dinv[v];
    float2 bb = ((const float2*)b1)[lane];
    float g0 = fmaxf(accx * dv + bb.x, 0.f) * dv;
    float g1 = fmaxf(accy * dv + bb.y, 0.f) * dv;
    __half2 h = __floats2half2_rn(g0, g1);
    ((unsigned int*)(gs + (size_t)v * 128))[lane] = *(unsigned int*)&h;
}

// ---- gather2 + LDS-pooled mean-pool accumulate ----
__global__ void gather2_pool(const __half* __restrict__ gs, const int* __restrict__ adj,
                             const int* __restrict__ offs, const int* __restrict__ deg,
                             const float* __restrict__ dinv, const int* __restrict__ batch,
                             float* __restrict__ poolsum, int n) {
    __shared__ float poolacc[128];
    int t = threadIdx.x;
    int wave = t >> 6;
    int lane = t & 63;
    if (t < 128) poolacc[t] = 0.f;
    int gref = batch[blockIdx.x * 4];                // first node always < n
    __syncthreads();
    int v = blockIdx.x * 4 + wave;
    if (v < n) {
        float2 a0 = make_float2(0.f, 0.f), a1 = a0, a2 = a0, a3 = a0;
        acc_h2(ROWP(gs, v)[lane], a0);
        int start = __builtin_amdgcn_readfirstlane(offs[v]);
        int d     = __builtin_amdgcn_readfirstlane(deg[v]);
        PIPE_GATHER(gs)
        float accx = (a0.x + a1.x) + (a2.x + a3.x);
        float accy = (a0.y + a1.y) + (a2.y + a3.y);
        float dv = dinv[v];
        int g = batch[v];
        if (g == gref) {
            atomicAdd(&poolacc[lane * 2 + 0], accx * dv);
            atomicAdd(&poolacc[lane * 2 + 1], accy * dv);
        } else {
            float* p = poolsum + (size_t)g * 128;
            atomicAdd(&p[lane * 2 + 0], accx * dv);
            atomicAdd(&p[lane * 2 + 1], accy * dv);
        }
    }
    __syncthreads();
    if (t < 128) {
        float s = poolacc[t];
        if (s != 0.f) atomicAdd(&poolsum[(size_t)gref * 128 + t], s);
    }
}

// ---- head: emb = (pool/cnt) @ W2 + b2 ; logits = emb @ Wg + bg ----
__global__ void head(const float* __restrict__ poolsum, const int* __restrict__ cnt,
                     const float* __restrict__ W2, const float* __restrict__ b2,
                     const float* __restrict__ Wg, const float* __restrict__ bg,
                     float* __restrict__ out, int G) {
    __shared__ float pm[128];
    __shared__ float emb[256];
    int g = blockIdx.x, t = threadIdx.x;
    float inv = 1.f / fmaxf((float)cnt[g], 1.f);
    if (t < 128) pm[t] = poolsum[(size_t)g * 128 + t] * inv;
    __syncthreads();
    float acc = b2[t];
    for (int k = 0; k < 128; ++k) acc += pm[k] * W2[k * 256 + t];
    out[(size_t)g * 256 + t] = acc;
    emb[t] = acc;
    __syncthreads();
    if (t < 16) {
        float a = bg[t];
        for (int j = 0; j < 256; ++j) a += emb[j] * Wg[j * 16 + t];
        out[(size_t)G * 256 + g * 16 + t] = a;
    }
}

extern "C" void kernel_launch(void* const* d_in, const int* in_sizes, int n_in,
                              void* d_out, int out_size, void* d_ws, size_t ws_size,
                              hipStream_t stream) {
    const float* x     = (const float*)d_in[0];
    const int*   ei    = (const int*)d_in[1];
    const int*   batch = (const int*)d_in[2];
    const float* W1    = (const float*)d_in[4];
    const float* b1    = (const float*)d_in[5];
    const float* W2    = (const float*)d_in[6];
    const float* b2    = (const float*)d_in[7];
    const float* Wg    = (const float*)d_in[8];
    const float* bg    = (const float*)d_in[9];
    float* out = (float*)d_out;

    int n = in_sizes[0] / 128;
    int E = in_sizes[1] / 2;
    int G = out_size / (256 + 16);
    int B = (n + 255) >> 8;                 // buckets of 256 nodes (<= 512)
    int nchunks = (E + CHUNK - 1) / CHUNK;  // <= 512

    char* ws = (char*)d_ws;
    auto alloc = [&](size_t bytes) {
        char* p = ws;
        ws += (bytes + 255) & ~(size_t)255;
        return p;
    };
    // ---- zeroed region (contiguous: ONE small memset) ----
    char*   zbase     = ws;
    int*    bucketTot = (int*)alloc((size_t)(B + 1) * 4);
    int*    cnt       = (int*)alloc((size_t)G * 4);
    float*  poolsum   = (float*)alloc((size_t)G * 128 * 4);
    size_t  zbytes    = (size_t)(ws - zbase);
    // ---- rest ----
    int*      deg     = (int*)alloc((size_t)n * 4);
    float*    dinv    = (float*)alloc((size_t)n * 4);
    int*      offs    = (int*)alloc((size_t)n * 4);
    int*      degSub  = (int*)alloc((size_t)SUBS * ((size_t)B << 8) * 4);
    int*      adj     = (int*)alloc((size_t)E * 4);
    unsigned* sorted  = (unsigned*)alloc((size_t)E * 4);
    int*      histT   = (int*)alloc((size_t)B * nchunks * 4);
    int*      sstartT = (int*)alloc((size_t)B * nchunks * 4);
    __half*   Wt      = (__half*)alloc(128 * 128 * 2);
    __half*   hs1     = (__half*)alloc((size_t)n * 128 * 2);
    __half*   gs1     = (__half*)alloc((size_t)n * 128 * 2);

    hipMemsetAsync(zbase, 0, zbytes, stream);

    k1_bucket<<<nchunks, 256, 0, stream>>>(ei, E, B, nchunks, sorted, histT, sstartT,
                                           bucketTot);
    k3a_deg<<<dim3(B, SUBS), 256, 0, stream>>>(sorted, histT, sstartT, degSub, B, nchunks);
    k3b_offs<<<B, 256, 0, stream>>>(degSub, bucketTot, batch, offs, deg, dinv, cnt, n, B);
    k3c_scatter<<<dim3(B, SUBS), 256, 0, stream>>>(sorted, histT, sstartT, degSub,
                                                   adj, B, nchunks);

    prep_wt<<<64, TPB, 0, stream>>>(W1, Wt);
    gemm1_mfma<<<(n + 63) / 64, 256, 0, stream>>>(x, Wt, dinv, hs1, n);
    gather1<<<(n + 3) / 4, 256, 0, stream>>>(hs1, adj, offs, deg, dinv, b1, gs1, n);
    gather2_pool<<<(n + 3) / 4, 256, 0, stream>>>(gs1, adj, offs, deg, dinv, batch, poolsum, n);
    head<<<G, 256, 0, stream>>>(poolsum, cnt, W2, b2, Wg, bg, out, G);
}